// Round 5
// baseline (1101.193 us; speedup 1.0000x reference)
//
#include <hip/hip_runtime.h>
#include <hip/hip_bf16.h>

typedef __hip_bfloat16 bf16;
typedef __bf16 bf16x8 __attribute__((ext_vector_type(8)));
typedef float f32x4 __attribute__((ext_vector_type(4)));

#define N_TOK 131072
#define C_DIM 256
#define HID_DIM 1024

// async global->LDS, 16B per lane; lds base must be wave-uniform (dest = base + lane*16)
__device__ __forceinline__ void async_copy16(void* lds, const void* g) {
  __builtin_amdgcn_global_load_lds(
      (const __attribute__((address_space(1))) void*)g,
      (__attribute__((address_space(3))) void*)lds, 16, 0, 0);
}

// wait all in-flight global_load_lds + ds ops, then block barrier (pipeline barrier)
#define PIPE_BARRIER() asm volatile("s_waitcnt vmcnt(0) lgkmcnt(0)\n\ts_barrier" ::: "memory")

__device__ __forceinline__ float fast_rcp(float x) {
#if __has_builtin(__builtin_amdgcn_rcpf)
  return __builtin_amdgcn_rcpf(x);
#else
  return 1.f / x;
#endif
}

// RNE float->bf16 in 3 VALU ops (valid for all finite values; no NaNs in this net)
__device__ __forceinline__ bf16 bf16_rne(float f) {
  unsigned u = __float_as_uint(f);
  u += 0x7FFF + ((u >> 16) & 1);
  unsigned short s = (unsigned short)(u >> 16);
  return *reinterpret_cast<bf16*>(&s);
}

// gelu tanh-approx via exact identity 0.5x(1+tanh(y)) = x*sigmoid(2y)
__device__ __forceinline__ float fast_gelu(float x) {
  float t = x * x;
  float u = __builtin_fmaf(0.07135481627f, t, 1.5957691216f);
  float z = x * u;
  float e = __expf(-z);
  return x * fast_rcp(1.f + e);
}

// ---------------- LN1: fp32 in -> bf16 out, one wave per row ----------------
__global__ void ln_bf16_kernel(const float* __restrict__ x,
                               const float* __restrict__ g,
                               const float* __restrict__ b,
                               bf16* __restrict__ out) {
  int row = blockIdx.x * 4 + threadIdx.y;
  int lane = threadIdx.x;
  size_t base = (size_t)row * C_DIM + lane * 4;
  float4 v = *(const float4*)(x + base);
  float s = v.x + v.y + v.z + v.w;
  float s2 = v.x * v.x + v.y * v.y + v.z * v.z + v.w * v.w;
#pragma unroll
  for (int m = 1; m < 64; m <<= 1) { s += __shfl_xor(s, m); s2 += __shfl_xor(s2, m); }
  float mean = s * (1.f / 256.f);
  float var = s2 * (1.f / 256.f) - mean * mean;
  float rstd = rsqrtf(var + 1e-5f);
  float4 gv = *(const float4*)(g + lane * 4);
  float4 bv = *(const float4*)(b + lane * 4);
  union { bf16 h[4]; uint2 u; } pk;
  pk.h[0] = bf16_rne((v.x - mean) * rstd * gv.x + bv.x);
  pk.h[1] = bf16_rne((v.y - mean) * rstd * gv.y + bv.y);
  pk.h[2] = bf16_rne((v.z - mean) * rstd * gv.z + bv.z);
  pk.h[3] = bf16_rne((v.w - mean) * rstd * gv.w + bv.w);
  *(uint2*)(out + base) = pk.u;
}

// weight [K,N] fp32 -> [N,K] bf16
__global__ void cast_transpose_kernel(const float* __restrict__ in, bf16* __restrict__ out,
                                      int K, int N) {
  int idx = blockIdx.x * 256 + threadIdx.x;
  if (idx >= K * N) return;
  int n = idx / K, k = idx - n * K;
  out[idx] = bf16_rne(in[(size_t)k * N + n]);
}

// ---- shared staging idioms ----
// A-tile [64 rows][256 k] bf16 in LDS, swizzled: LDS[row][cb] = G[row][cb ^ (row&7)]
// (cb = 16B block of 8 bf16). Frag read of k-block kb at row r: cb' = kb ^ (r&7)
// -> 8 distinct bank groups x 2 lanes = conflict-free. Staged via 8 wave-issues of
// 1KB (dest = uniform base + lane*16, source col-block XOR-permuted within the row).

// ---------------- QKV GEMM: A[64x256]-resident, B streamed dbuf -------------
// out[m, 768] = ln1 @ wqkv + b. 256 thr / 4 waves; per n-chunk(128): waves 2Mx2N.
__global__ __launch_bounds__(256) void qkv_gemm_kernel(
    const bf16* __restrict__ A, const bf16* __restrict__ Bt,
    const float* __restrict__ bias, bf16* __restrict__ out) {
  __shared__ bf16 sA[64 * 256];
  __shared__ bf16 sB[2][128 * 32];
  const int tid = threadIdx.x, wid = tid >> 6, lane = tid & 63;
  const int quad = lane >> 4, l16 = lane & 15;
  const int m0 = blockIdx.x * 64;

  // stage A (8 issues x 1KB/wave)
#pragma unroll
  for (int s = 0; s < 8; ++s) {
    int r0 = (s * 4 + wid) * 2;
    int row = r0 + (lane >> 5), cb = lane & 31;
    async_copy16(&sA[r0 * 256],
                 &A[(size_t)(m0 + row) * 256 + ((cb ^ (row & 7)) << 3)]);
  }
  // stage B chunk 0 (nc=0,kc=0)
  {
#pragma unroll
    for (int s = 0; s < 2; ++s) {
      int n0 = s * 64 + wid * 16;
      int n = n0 + (lane >> 2), cb = lane & 3;
      async_copy16(&sB[0][n0 * 32],
                   &Bt[(size_t)n * 256 + ((cb ^ ((n >> 1) & 3)) << 3)]);
    }
  }

  bf16x8 af[2][8];
  f32x4 acc[2][4];

  for (int i = 0; i < 48; ++i) {  // 6 n-chunks x 8 k-chunks
    const int nc = i >> 3, kc = i & 7;
    PIPE_BARRIER();
    if (i == 0) {  // hoist A-frags into registers once
#pragma unroll
      for (int i2 = 0; i2 < 2; ++i2)
#pragma unroll
        for (int ks = 0; ks < 8; ++ks) {
          int row = (wid & 1) * 32 + i2 * 16 + l16;
          af[i2][ks] = *(const bf16x8*)&sA[row * 256 + (((ks * 4 + quad) ^ (row & 7)) << 3)];
        }
    }
    if (i + 1 < 48) {  // prefetch next B chunk into other buffer
      const int nc2 = (i + 1) >> 3, kc2 = (i + 1) & 7, nb = (i + 1) & 1;
#pragma unroll
      for (int s = 0; s < 2; ++s) {
        int n0 = s * 64 + wid * 16;
        int n = n0 + (lane >> 2), cb = lane & 3;
        async_copy16(&sB[nb][n0 * 32],
                     &Bt[(size_t)(nc2 * 128 + n) * 256 + kc2 * 32 + ((cb ^ ((n >> 1) & 3)) << 3)]);
      }
    }
    if (kc == 0) {
#pragma unroll
      for (int i2 = 0; i2 < 2; ++i2)
#pragma unroll
        for (int j = 0; j < 4; ++j) acc[i2][j] = (f32x4){0.f, 0.f, 0.f, 0.f};
    }
    const bf16* bs = sB[i & 1];
#pragma unroll
    for (int j = 0; j < 4; ++j) {
      int n = (wid >> 1) * 64 + j * 16 + l16;
      bf16x8 bfr = *(const bf16x8*)&bs[n * 32 + ((quad ^ ((l16 >> 1) & 3)) << 3)];
#pragma unroll
      for (int i2 = 0; i2 < 2; ++i2)
        acc[i2][j] = __builtin_amdgcn_mfma_f32_16x16x32_bf16(af[i2][kc], bfr, acc[i2][j], 0, 0, 0);
    }
    if (kc == 7) {  // epilogue for this n-chunk
#pragma unroll
      for (int i2 = 0; i2 < 2; ++i2) {
        int rowb = m0 + (wid & 1) * 32 + i2 * 16 + quad * 4;
#pragma unroll
        for (int j = 0; j < 4; ++j) {
          int col = nc * 128 + (wid >> 1) * 64 + j * 16 + l16;
          float bv = bias[col];
#pragma unroll
          for (int r = 0; r < 4; ++r)
            out[(size_t)(rowb + r) * 768 + col] = bf16_rne(acc[i2][j][r] + bv);
        }
      }
    }
  }
}

// -------- proj GEMM + residual + LN2 fused. Whole-row waves (16 rows each) ---
// xres = bf16(feat + attn_o@wproj + b); ln2 = bf16(LN(that, g, b)).
__global__ __launch_bounds__(256) void proj_ln2_kernel(
    const bf16* __restrict__ A, const bf16* __restrict__ Bt,
    const float* __restrict__ bias, const float* __restrict__ res,
    const float* __restrict__ g, const float* __restrict__ b,
    bf16* __restrict__ xres, bf16* __restrict__ ln2out) {
  __shared__ bf16 sA[64 * 256];
  __shared__ bf16 sB[2][256 * 32];
  const int tid = threadIdx.x, wid = tid >> 6, lane = tid & 63;
  const int quad = lane >> 4, l16 = lane & 15;
  const int m0 = blockIdx.x * 64;

#pragma unroll
  for (int s = 0; s < 8; ++s) {
    int r0 = (s * 4 + wid) * 2;
    int row = r0 + (lane >> 5), cb = lane & 31;
    async_copy16(&sA[r0 * 256],
                 &A[(size_t)(m0 + row) * 256 + ((cb ^ (row & 7)) << 3)]);
  }
#pragma unroll
  for (int s = 0; s < 4; ++s) {
    int n0 = s * 64 + wid * 16;
    int n = n0 + (lane >> 2), cb = lane & 3;
    async_copy16(&sB[0][n0 * 32],
                 &Bt[(size_t)n * 256 + ((cb ^ ((n >> 1) & 3)) << 3)]);
  }

  bf16x8 af[8];
  f32x4 acc[16] = {};

  for (int kc = 0; kc < 8; ++kc) {
    PIPE_BARRIER();
    if (kc == 0) {
#pragma unroll
      for (int ks = 0; ks < 8; ++ks) {
        int row = wid * 16 + l16;
        af[ks] = *(const bf16x8*)&sA[row * 256 + (((ks * 4 + quad) ^ (row & 7)) << 3)];
      }
    }
    if (kc < 7) {
      const int nb = (kc + 1) & 1;
#pragma unroll
      for (int s = 0; s < 4; ++s) {
        int n0 = s * 64 + wid * 16;
        int n = n0 + (lane >> 2), cb = lane & 3;
        async_copy16(&sB[nb][n0 * 32],
                     &Bt[(size_t)n * 256 + (kc + 1) * 32 + ((cb ^ ((n >> 1) & 3)) << 3)]);
      }
    }
    const bf16* bs = sB[kc & 1];
#pragma unroll
    for (int j = 0; j < 16; ++j) {
      int n = j * 16 + l16;
      bf16x8 bfr = *(const bf16x8*)&bs[n * 32 + ((quad ^ ((l16 >> 1) & 3)) << 3)];
      acc[j] = __builtin_amdgcn_mfma_f32_16x16x32_bf16(af[kc], bfr, acc[j], 0, 0, 0);
    }
  }

  // epilogue: v = acc + bias + res; per-row LN via quad shuffles (row = quad-local)
  const int rowq = m0 + wid * 16 + quad * 4;
  float s1[4] = {0.f, 0.f, 0.f, 0.f}, s2[4] = {0.f, 0.f, 0.f, 0.f};
#pragma unroll
  for (int j = 0; j < 16; ++j) {
    int col = j * 16 + l16;
    float bv = bias[col];
#pragma unroll
    for (int r = 0; r < 4; ++r) {
      float v = acc[j][r] + bv + res[(size_t)(rowq + r) * 256 + col];
      acc[j][r] = v;
      s1[r] += v;
      s2[r] += v * v;
    }
  }
#pragma unroll
  for (int r = 0; r < 4; ++r)
#pragma unroll
    for (int mk = 1; mk < 16; mk <<= 1) {
      s1[r] += __shfl_xor(s1[r], mk);
      s2[r] += __shfl_xor(s2[r], mk);
    }
  float mean[4], rstd[4];
#pragma unroll
  for (int r = 0; r < 4; ++r) {
    mean[r] = s1[r] * (1.f / 256.f);
    float var = s2[r] * (1.f / 256.f) - mean[r] * mean[r];
    rstd[r] = rsqrtf(var + 1e-5f);
  }
#pragma unroll
  for (int j = 0; j < 16; ++j) {
    int col = j * 16 + l16;
    float gv = g[col], bl = b[col];
#pragma unroll
    for (int r = 0; r < 4; ++r) {
      size_t idx = (size_t)(rowq + r) * 256 + col;
      float v = acc[j][r];
      xres[idx] = bf16_rne(v);
      ln2out[idx] = bf16_rne((v - mean[r]) * rstd[r] * gv + bl);
    }
  }
}

// ------- fused MLP: out = xres + gelu(ln2@w1+b1)@w2 + b2, h stays in LDS -----
// 512 thr / 8 waves, m-tile 128. 32 hidden-chunks of 32.
__global__ __launch_bounds__(512) void mlp_fused_kernel(
    const bf16* __restrict__ A, const bf16* __restrict__ W1t,
    const float* __restrict__ b1, const bf16* __restrict__ W2t,
    const float* __restrict__ b2, const bf16* __restrict__ res,
    float* __restrict__ out) {
  __shared__ bf16 sA[128 * 256];  // 64KB, ln2 m-tile (resident)
  __shared__ bf16 sW1[32 * 256];  // 16KB, w1T chunk [32 hid][256 k]
  __shared__ bf16 sW2[256 * 32];  // 16KB, w2T chunk [256 n][32 k]
  __shared__ bf16 sH[128 * 40];   // 10KB, gelu chunk, +8 pad
  const int tid = threadIdx.x, w = tid >> 6, lane = tid & 63;
  const int quad = lane >> 4, l16 = lane & 15;
  const int m0 = blockIdx.x * 128;
  const int q1 = (w & 3) * 32;        // GEMM1 m-quarter
  const int nh = (w >> 2) * 16;       // GEMM1 n-half

  // stage A (8 issues x 8KB)
#pragma unroll
  for (int s = 0; s < 8; ++s) {
    int r0 = (s * 8 + w) * 2;
    int row = r0 + (lane >> 5), cb = lane & 31;
    async_copy16(&sA[r0 * 256],
                 &A[(size_t)(m0 + row) * 256 + ((cb ^ (row & 7)) << 3)]);
  }

  bf16x8 af1[2][8];
  f32x4 acc2[16] = {};

  for (int c = 0; c < 32; ++c) {
    __syncthreads();  // WAR: prior chunk's LDS reads done (c=0: A-stage drain via vmcnt0)
    // stage w1 chunk [c*32 .. +32)
#pragma unroll
    for (int s = 0; s < 2; ++s) {
      int r0 = s * 16 + w * 2;
      int row = r0 + (lane >> 5), cb = lane & 31;
      async_copy16(&sW1[r0 * 256],
                   &W1t[(size_t)(c * 32 + row) * 256 + ((cb ^ (row & 7)) << 3)]);
    }
    // stage w2 chunk [all 256 n][c*32 .. +32)
#pragma unroll
    for (int s = 0; s < 2; ++s) {
      int n0 = s * 128 + w * 16;
      int n = n0 + (lane >> 2), cb = lane & 3;
      async_copy16(&sW2[n0 * 32],
                   &W2t[(size_t)n * 1024 + c * 32 + ((cb ^ ((n >> 1) & 3)) << 3)]);
    }
    __syncthreads();  // staged visible (drains vmcnt0; covers A on first pass)
    if (c == 0) {
#pragma unroll
      for (int i = 0; i < 2; ++i)
#pragma unroll
        for (int ks = 0; ks < 8; ++ks) {
          int row = q1 + i * 16 + l16;
          af1[i][ks] = *(const bf16x8*)&sA[row * 256 + (((ks * 4 + quad) ^ (row & 7)) << 3)];
        }
    }
    // GEMM1: h[128x32] chunk
    f32x4 a1[2] = {};
#pragma unroll
    for (int ks = 0; ks < 8; ++ks) {
      int n = nh + l16;
      bf16x8 b1f = *(const bf16x8*)&sW1[n * 256 + (((ks * 4 + quad) ^ (n & 7)) << 3)];
#pragma unroll
      for (int i = 0; i < 2; ++i)
        a1[i] = __builtin_amdgcn_mfma_f32_16x16x32_bf16(af1[i][ks], b1f, a1[i], 0, 0, 0);
    }
    // gelu -> sH
    float bb = b1[c * 32 + nh + l16];
#pragma unroll
    for (int i = 0; i < 2; ++i) {
      int rowb = q1 + i * 16 + quad * 4;
#pragma unroll
      for (int r = 0; r < 4; ++r)
        sH[(rowb + r) * 40 + nh + l16] = bf16_rne(fast_gelu(a1[i][r] + bb));
    }
    __syncthreads();  // h visible
    // GEMM2: acc2 += h_chunk @ w2_chunk
    {
      int m = w * 16 + l16;
      bf16x8 a2f = *(const bf16x8*)&sH[m * 40 + quad * 8];
#pragma unroll
      for (int j = 0; j < 16; ++j) {
        int n = j * 16 + l16;
        bf16x8 b2f = *(const bf16x8*)&sW2[n * 32 + ((quad ^ ((l16 >> 1) & 3)) << 3)];
        acc2[j] = __builtin_amdgcn_mfma_f32_16x16x32_bf16(a2f, b2f, acc2[j], 0, 0, 0);
      }
    }
  }

  // epilogue: out = acc2 + b2 + res (bf16 residual), fp32 store
  const int rowq = m0 + w * 16 + quad * 4;
#pragma unroll
  for (int j = 0; j < 16; ++j) {
    int col = j * 16 + l16;
    float bv = b2[col];
#pragma unroll
    for (int r = 0; r < 4; ++r) {
      size_t idx = (size_t)(rowq + r) * 256 + col;
      out[idx] = acc2[j][r] + bv + __bfloat162float(res[idx]);
    }
  }
}

// ---------------- attention (unchanged from r3: XCD-swizzled) ----------------
__global__ __launch_bounds__(256) void attn_kernel(
    const bf16* __restrict__ qkv, const int* __restrict__ order,
    bf16* __restrict__ outw) {
  __shared__ bf16 sK[128 * 40];
  __shared__ bf16 sVt[32 * 136];
  __shared__ bf16 sP[128 * 136];
  __shared__ int sOrd[128];
  const int bid = blockIdx.x;
  const int h = (bid >> 3) & 7;
  const int p = ((bid >> 6) << 3) | (bid & 7);
  const int tid = threadIdx.x;
  const int wid = tid >> 6;
  const int lane = tid & 63;
  const int quad = lane >> 4;
  const int l16 = lane & 15;

  if (tid < 128) sOrd[tid] = order[p * 128 + tid];
  __syncthreads();

  {
    int r = tid >> 1;
    int half = (tid & 1) * 16;
    size_t base = (size_t)sOrd[r] * 768 + h * 32;
    uint4 ka = *(const uint4*)&qkv[base + 256 + half];
    uint4 kb = *(const uint4*)&qkv[base + 256 + half + 8];
    *(uint4*)&sK[r * 40 + half] = ka;
    *(uint4*)&sK[r * 40 + half + 8] = kb;
    union { uint4 u[2]; bf16 e[16]; } vv;
    vv.u[0] = *(const uint4*)&qkv[base + 512 + half];
    vv.u[1] = *(const uint4*)&qkv[base + 512 + half + 8];
#pragma unroll
    for (int c = 0; c < 16; ++c) sVt[(half + c) * 136 + r] = vv.e[c];
  }
  __syncthreads();

  bf16x8 qf[2];
#pragma unroll
  for (int t = 0; t < 2; ++t) {
    int r = wid * 32 + t * 16 + l16;
    qf[t] = *(const bf16x8*)&qkv[(size_t)sOrd[r] * 768 + h * 32 + quad * 8];
  }

  const f32x4 zero = {0.f, 0.f, 0.f, 0.f};
  f32x4 s[2][8];
#pragma unroll
  for (int ct = 0; ct < 8; ++ct) {
    bf16x8 kf = *(const bf16x8*)&sK[(ct * 16 + l16) * 40 + quad * 8];
#pragma unroll
    for (int t = 0; t < 2; ++t)
      s[t][ct] = __builtin_amdgcn_mfma_f32_16x16x32_bf16(qf[t], kf, zero, 0, 0, 0);
  }

  const float scale = 0.17677669529663687f;
#pragma unroll
  for (int t = 0; t < 2; ++t) {
#pragma unroll
    for (int r = 0; r < 4; ++r) {
      float mx = -1e30f;
#pragma unroll
      for (int ct = 0; ct < 8; ++ct) mx = fmaxf(mx, s[t][ct][r]);
      mx *= scale;
#pragma unroll
      for (int mk = 1; mk < 16; mk <<= 1) mx = fmaxf(mx, __shfl_xor(mx, mk));
      float sum = 0.f;
#pragma unroll
      for (int ct = 0; ct < 8; ++ct) {
        float e = __expf(scale * s[t][ct][r] - mx);
        s[t][ct][r] = e;
        sum += e;
      }
#pragma unroll
      for (int mk = 1; mk < 16; mk <<= 1) sum += __shfl_xor(sum, mk);
      float inv = fast_rcp(sum);
      int prow = wid * 32 + t * 16 + quad * 4 + r;
#pragma unroll
      for (int ct = 0; ct < 8; ++ct)
        sP[prow * 136 + ct * 16 + l16] = bf16_rne(s[t][ct][r] * inv);
    }
  }
  __syncthreads();

  f32x4 o[2][2] = {};
#pragma unroll
  for (int ks = 0; ks < 4; ++ks) {
    bf16x8 vf[2];
#pragma unroll
    for (int n = 0; n < 2; ++n)
      vf[n] = *(const bf16x8*)&sVt[(n * 16 + l16) * 136 + ks * 32 + quad * 8];
#pragma unroll
    for (int t = 0; t < 2; ++t) {
      bf16x8 pf = *(const bf16x8*)&sP[(wid * 32 + t * 16 + l16) * 136 + ks * 32 + quad * 8];
#pragma unroll
      for (int n = 0; n < 2; ++n)
        o[t][n] = __builtin_amdgcn_mfma_f32_16x16x32_bf16(pf, vf[n], o[t][n], 0, 0, 0);
    }
  }

#pragma unroll
  for (int t = 0; t < 2; ++t) {
    int rowb = wid * 32 + t * 16 + quad * 4;
#pragma unroll
    for (int r = 0; r < 4; ++r) {
      size_t gbase = (size_t)sOrd[rowb + r] * 256 + h * 32;
#pragma unroll
      for (int n = 0; n < 2; ++n)
        outw[gbase + n * 16 + l16] = bf16_rne(o[t][n][r]);
    }
  }
}

extern "C" void kernel_launch(void* const* d_in, const int* in_sizes, int n_in,
                              void* d_out, int out_size, void* d_ws, size_t ws_size,
                              hipStream_t stream) {
  const float* feat   = (const float*)d_in[0];
  const float* ln1_g  = (const float*)d_in[1];
  const float* ln1_b  = (const float*)d_in[2];
  const float* w_qkv  = (const float*)d_in[3];
  const float* b_qkv  = (const float*)d_in[4];
  const float* w_proj = (const float*)d_in[5];
  const float* b_proj = (const float*)d_in[6];
  const float* ln2_g  = (const float*)d_in[7];
  const float* ln2_b  = (const float*)d_in[8];
  const float* w1     = (const float*)d_in[9];
  const float* b1     = (const float*)d_in[10];
  const float* w2     = (const float*)d_in[11];
  const float* b2     = (const float*)d_in[12];
  const int* order    = (const int*)d_in[13];
  float* out = (float*)d_out;

  char* ws = (char*)d_ws;
  size_t off = 0;
  auto take = [&](size_t bytes) {
    char* pp = ws + off;
    off += (bytes + 255) & ~(size_t)255;
    return pp;
  };
  bf16* ln_buf  = (bf16*)take((size_t)N_TOK * 256 * 2);  // ln1; reused as ln2 target
  bf16* qkv     = (bf16*)take((size_t)N_TOK * 768 * 2);
  bf16* attn_o  = (bf16*)take((size_t)N_TOK * 256 * 2);
  bf16* xresb   = (bf16*)take((size_t)N_TOK * 256 * 2);  // residual stream, bf16
  bf16* wqkvT   = (bf16*)take(768 * 256 * 2);
  bf16* wprojT  = (bf16*)take(256 * 256 * 2);
  bf16* w1T     = (bf16*)take(1024 * 256 * 2);
  bf16* w2T     = (bf16*)take(256 * 1024 * 2);

  cast_transpose_kernel<<<768, 256, 0, stream>>>(w_qkv, wqkvT, 256, 768);
  cast_transpose_kernel<<<256, 256, 0, stream>>>(w_proj, wprojT, 256, 256);
  cast_transpose_kernel<<<1024, 256, 0, stream>>>(w1, w1T, 256, 1024);
  cast_transpose_kernel<<<1024, 256, 0, stream>>>(w2, w2T, 1024, 256);

  ln_bf16_kernel<<<N_TOK / 4, dim3(64, 4), 0, stream>>>(feat, ln1_g, ln1_b, ln_buf);
  qkv_gemm_kernel<<<N_TOK / 64, 256, 0, stream>>>(ln_buf, wqkvT, b_qkv, qkv);
  attn_kernel<<<8 * 1024, 256, 0, stream>>>(qkv, order, attn_o);
  proj_ln2_kernel<<<N_TOK / 64, 256, 0, stream>>>(attn_o, wprojT, b_proj, feat,
                                                  ln2_g, ln2_b, xresb, ln_buf);
  mlp_fused_kernel<<<N_TOK / 128, 512, 0, stream>>>(ln_buf, w1T, b1, w2T, b2, xresb, out);
}